// Round 1
// baseline (338.479 us; speedup 1.0000x reference)
//
#include <hip/hip_runtime.h>
#include <hip/hip_bf16.h>

#define IN_F 512
#define OUT_F 512
#define LATD 512
#define RES 64
#define BATCH 8
#define EPSV 1e-8f

static constexpr float C_LIN  = 0.04419417382415922f;   // 1/sqrt(512)
static constexpr float C_CONV = 0.014731391274719739f;  // 1/sqrt(512*9)

typedef __attribute__((ext_vector_type(8))) short short8;
typedef __attribute__((ext_vector_type(4))) float f32x4;

// ---------------- s = latent @ (w_lin*C).T + b_lin ----------------
__global__ void k_compute_s(const float* __restrict__ latent,
                            const float* __restrict__ w_lin,
                            const float* __restrict__ b_lin,
                            float* __restrict__ s) {
  const int i = blockIdx.x;       // output feature
  const int lane = threadIdx.x;   // 0..63
  float acc[BATCH];
#pragma unroll
  for (int b = 0; b < BATCH; ++b) acc[b] = 0.f;
  for (int l = lane; l < LATD; l += 64) {
    const float wv = w_lin[i * LATD + l];
#pragma unroll
    for (int b = 0; b < BATCH; ++b) acc[b] += wv * latent[b * LATD + l];
  }
#pragma unroll
  for (int b = 0; b < BATCH; ++b) {
    float v = acc[b];
#pragma unroll
    for (int off = 32; off > 0; off >>= 1) v += __shfl_down(v, off);
    if (lane == 0) s[b * IN_F + i] = v * C_LIN + b_lin[i];
  }
}

// ---- wb[o][tap][i] = bf16(w_conv[o][i][tap]*C), w2[o][i] = sum_tap w^2 ----
__global__ void k_prep_w(const float* __restrict__ w_conv,
                         __hip_bfloat16* __restrict__ wb,
                         float* __restrict__ w2) {
  const int idx = blockIdx.x * 256 + threadIdx.x;  // o*512 + i
  const int o = idx >> 9;
  const int i = idx & 511;
  const float* src = w_conv + idx * 9;
  float sum = 0.f;
#pragma unroll
  for (int t = 0; t < 9; ++t) {
    const float v = src[t] * C_CONV;
    wb[(o * 9 + t) * IN_F + i] = __float2bfloat16(v);
    sum += v * v;
  }
  w2[idx] = sum;
}

// ---- sigma_inv[b][o] = rsqrt(sum_i w2[o][i]*s[b][i]^2 + eps) ----
__global__ void k_compute_sigma(const float* __restrict__ w2,
                                const float* __restrict__ s,
                                float* __restrict__ sigma_inv) {
  const int o = blockIdx.x;
  const int lane = threadIdx.x;
  float acc[BATCH];
#pragma unroll
  for (int b = 0; b < BATCH; ++b) acc[b] = 0.f;
  for (int i = lane; i < IN_F; i += 64) {
    const float w = w2[o * IN_F + i];
#pragma unroll
    for (int b = 0; b < BATCH; ++b) {
      const float sv = s[b * IN_F + i];
      acc[b] += w * sv * sv;
    }
  }
#pragma unroll
  for (int b = 0; b < BATCH; ++b) {
    float v = acc[b];
#pragma unroll
    for (int off = 32; off > 0; off >>= 1) v += __shfl_down(v, off);
    if (lane == 0) sigma_inv[b * OUT_F + o] = rsqrtf(v + EPSV);
  }
}

// ---- xm[b][h][w][i] = bf16(x[b][i][h][w] * s[b][i])  (NCHW -> NHWC) ----
__global__ void k_modulate(const float* __restrict__ x,
                           const float* __restrict__ s,
                           __hip_bfloat16* __restrict__ xm) {
  const int blk = blockIdx.x;          // b(8) x h(64) x ic(16)
  const int ic = blk & 15;
  const int h  = (blk >> 4) & 63;
  const int b  = blk >> 10;
  __shared__ float tile[32][65];
  const int tid = threadIdx.x;
#pragma unroll
  for (int j = 0; j < 8; ++j) {
    const int e = tid + j * 256;       // 0..2047 over (il, w)
    const int il = e >> 6;
    const int w  = e & 63;
    const int i = ic * 32 + il;
    tile[il][w] = x[((b * IN_F + i) * RES + h) * RES + w] * s[b * IN_F + i];
  }
  __syncthreads();
#pragma unroll
  for (int j = 0; j < 8; ++j) {
    const int e = tid + j * 256;       // (w, il) — il contiguous in memory
    const int w  = e >> 5;
    const int il = e & 31;
    xm[((b * RES + h) * RES + w) * IN_F + ic * 32 + il] = __float2bfloat16(tile[il][w]);
  }
}

// ---------------- main implicit-GEMM conv ----------------
#define BN 64
#define CELL 40        // bf16 units per cell: 32 data + 8 pad = 80 B (16B-aligned, 2-way-free banks)
#define XROWS 6
#define XCOLS 66

__global__ __launch_bounds__(256, 2)
void k_conv(const __hip_bfloat16* __restrict__ xm,
            const __hip_bfloat16* __restrict__ wb,
            const float* __restrict__ sigma_inv,
            const float* __restrict__ b_conv,
            float* __restrict__ out) {
  __shared__ short xs[XROWS * XCOLS * CELL];   // 31680 B
  __shared__ short wsm[BN * 9 * CELL];         // 46080 B  (cell = ol*9 + tap)
  const int o0 = blockIdx.x * BN;
  const int mb = blockIdx.y;                   // 0..127 : b(8) x hquad(16)
  const int b  = mb >> 4;
  const int h0 = (mb & 15) << 2;
  const int tid  = threadIdx.x;
  const int wave = tid >> 6;                   // row within block tile
  const int lane = tid & 63;
  const int lo   = lane & 15;
  const int quad = lane >> 4;

  f32x4 acc[4][4];
#pragma unroll
  for (int i = 0; i < 4; ++i)
#pragma unroll
    for (int j = 0; j < 4; ++j) acc[i][j] = (f32x4){0.f, 0.f, 0.f, 0.f};

  const char* xs_base = (const char*)xs + (wave * XCOLS + lo) * (CELL * 2) + quad * 16;
  const char* ws_base = (const char*)wsm + (lo * 9) * (CELL * 2) + quad * 16;

  for (int ic = 0; ic < 16; ++ic) {
    const int i0 = ic * 32;
    __syncthreads();
    // stage x halo tile: 6 rows x 66 cols x 32 ch (4 x 16B parts per cell)
    for (int t = tid; t < XROWS * XCOLS * 4; t += 256) {
      const int cell = t >> 2;
      const int part = t & 3;
      const int r = cell / XCOLS;
      const int c = cell - r * XCOLS;
      const int h = h0 - 1 + r;
      const int w = c - 1;
      uint4 v = make_uint4(0u, 0u, 0u, 0u);
      if ((unsigned)h < (unsigned)RES && (unsigned)w < (unsigned)RES) {
        v = *(const uint4*)(xm + (((b * RES + h) * RES + w) * IN_F + i0 + part * 8));
      }
      *(uint4*)((char*)xs + cell * (CELL * 2) + part * 16) = v;
    }
    // stage weights: 64 o x 9 taps x 32 ch
    for (int t = tid; t < BN * 9 * 4; t += 256) {
      const int cell = t >> 2;
      const int part = t & 3;
      const int ol  = cell / 9;
      const int tap = cell - ol * 9;
      const uint4 v = *(const uint4*)(wb + ((((o0 + ol) * 9) + tap) * IN_F + i0 + part * 8));
      *(uint4*)((char*)wsm + cell * (CELL * 2) + part * 16) = v;
    }
    __syncthreads();
#pragma unroll
    for (int dh = 0; dh < 3; ++dh) {
#pragma unroll
      for (int dw = 0; dw < 3; ++dw) {
        const int tap = dh * 3 + dw;
        short8 bfrag[4];
#pragma unroll
        for (int ns = 0; ns < 4; ++ns) {
          bfrag[ns] = *(const short8*)(ws_base + (ns * 16 * 9 + tap) * (CELL * 2));
        }
#pragma unroll
        for (int ms = 0; ms < 4; ++ms) {
          const short8 afrag = *(const short8*)(xs_base + (dh * XCOLS + ms * 16 + dw) * (CELL * 2));
#pragma unroll
          for (int ns = 0; ns < 4; ++ns) {
            acc[ms][ns] = __builtin_amdgcn_mfma_f32_16x16x32_bf16(afrag, bfrag[ns], acc[ms][ns], 0, 0, 0);
          }
        }
      }
    }
  }
  // epilogue: y = acc * sigma_inv[b][o] + b_conv[o]
  const int h = h0 + wave;
#pragma unroll
  for (int ns = 0; ns < 4; ++ns) {
    const int o = o0 + ns * 16 + lo;
    const float sig  = sigma_inv[b * OUT_F + o];
    const float bias = b_conv[o];
    float* outp = out + (((b * OUT_F + o) * RES + h) * RES);
#pragma unroll
    for (int ms = 0; ms < 4; ++ms) {
      f32x4 v;
#pragma unroll
      for (int r = 0; r < 4; ++r) v[r] = acc[ms][ns][r] * sig + bias;
      *(f32x4*)(outp + ms * 16 + quad * 4) = v;
    }
  }
}

extern "C" void kernel_launch(void* const* d_in, const int* in_sizes, int n_in,
                              void* d_out, int out_size, void* d_ws, size_t ws_size,
                              hipStream_t stream) {
  const float* x      = (const float*)d_in[0];
  const float* latent = (const float*)d_in[1];
  const float* w_lin  = (const float*)d_in[2];
  const float* b_lin  = (const float*)d_in[3];
  const float* w_conv = (const float*)d_in[4];
  const float* b_conv = (const float*)d_in[5];
  float* out = (float*)d_out;

  char* ws = (char*)d_ws;
  __hip_bfloat16* xm = (__hip_bfloat16*)ws;                    // 33554432 B
  __hip_bfloat16* wb = (__hip_bfloat16*)(ws + 33554432);       //  4718592 B
  float* s           = (float*)(ws + 38273024);                //    16384 B
  float* w2          = (float*)(ws + 38289408);                //  1048576 B
  float* sigma_inv   = (float*)(ws + 39337984);                //    16384 B

  k_compute_s<<<512, 64, 0, stream>>>(latent, w_lin, b_lin, s);
  k_prep_w<<<(OUT_F * IN_F) / 256, 256, 0, stream>>>(w_conv, wb, w2);
  k_compute_sigma<<<512, 64, 0, stream>>>(w2, s, sigma_inv);
  k_modulate<<<BATCH * RES * 16, 256, 0, stream>>>(x, s, xm);
  dim3 grid(OUT_F / BN, BATCH * 16);
  k_conv<<<grid, 256, 0, stream>>>(xm, wb, sigma_inv, b_conv, out);
}

// Round 2
// 273.557 us; speedup vs baseline: 1.2373x; 1.2373x over previous
//
#include <hip/hip_runtime.h>
#include <hip/hip_bf16.h>

#define IN_F 512
#define OUT_F 512
#define LATD 512
#define RES 64
#define BATCH 8
#define EPSV 1e-8f

static constexpr float C_LIN  = 0.04419417382415922f;   // 1/sqrt(512)
static constexpr float C_CONV = 0.014731391274719739f;  // 1/sqrt(512*9)

typedef __attribute__((ext_vector_type(8))) short short8;
typedef __attribute__((ext_vector_type(4))) float f32x4;

union BF { __hip_bfloat16 h; short s; };

__device__ __forceinline__ void async_load16(const char* g, char* l) {
  __builtin_amdgcn_global_load_lds(
      (const __attribute__((address_space(1))) unsigned int*)g,
      (__attribute__((address_space(3))) unsigned int*)l, 16, 0, 0);
}

// ---------------- s = latent @ (w_lin*C).T + b_lin ----------------
__global__ void k_compute_s(const float* __restrict__ latent,
                            const float* __restrict__ w_lin,
                            const float* __restrict__ b_lin,
                            float* __restrict__ s) {
  const int i = blockIdx.x;
  const int lane = threadIdx.x;
  float acc[BATCH];
#pragma unroll
  for (int b = 0; b < BATCH; ++b) acc[b] = 0.f;
  for (int l = lane; l < LATD; l += 64) {
    const float wv = w_lin[i * LATD + l];
#pragma unroll
    for (int b = 0; b < BATCH; ++b) acc[b] += wv * latent[b * LATD + l];
  }
#pragma unroll
  for (int b = 0; b < BATCH; ++b) {
    float v = acc[b];
#pragma unroll
    for (int off = 32; off > 0; off >>= 1) v += __shfl_down(v, off);
    if (lane == 0) s[b * IN_F + i] = v * C_LIN + b_lin[i];
  }
}

// ---- wb[ic][tap][o][32ch] = bf16(w_conv[o][ic*32+ch][tap] * C_CONV) ----
__global__ void k_prep_w(const float* __restrict__ w_conv,
                         short* __restrict__ wb) {
  const int t = blockIdx.x * 256 + threadIdx.x;   // 294912 total
  const int part = t & 3;
  const int u = t >> 2;
  const int o = u & 511;
  const int v = u >> 9;        // 0..143 = ic*9+tap
  const int ic = v / 9;
  const int tap = v - ic * 9;
  short8 pk;
#pragma unroll
  for (int j = 0; j < 8; ++j) {
    const int i = ic * 32 + part * 8 + j;
    BF cv; cv.h = __float2bfloat16(w_conv[((size_t)o * IN_F + i) * 9 + tap] * C_CONV);
    pk[j] = cv.s;
  }
  *(short8*)(wb + (((size_t)(ic * 9 + tap) * OUT_F + o) * 32 + part * 8)) = pk;
}

// ---- sigma_inv[b][o] = rsqrt(sum_i (C^2*sum_t w^2) * s^2 + eps) ----
__global__ void k_sigma(const float* __restrict__ w_conv,
                        const float* __restrict__ s,
                        float* __restrict__ sigma_inv) {
  const int o = blockIdx.x;
  const int lane = threadIdx.x;
  float acc[BATCH];
#pragma unroll
  for (int b = 0; b < BATCH; ++b) acc[b] = 0.f;
  for (int i = lane; i < IN_F; i += 64) {
    const float* wp = w_conv + (size_t)(o * IN_F + i) * 9;
    float w2 = 0.f;
#pragma unroll
    for (int t = 0; t < 9; ++t) { const float w = wp[t] * C_CONV; w2 += w * w; }
#pragma unroll
    for (int b = 0; b < BATCH; ++b) {
      const float sv = s[b * IN_F + i];
      acc[b] += w2 * sv * sv;
    }
  }
#pragma unroll
  for (int b = 0; b < BATCH; ++b) {
    float v = acc[b];
#pragma unroll
    for (int off = 32; off > 0; off >>= 1) v += __shfl_down(v, off);
    if (lane == 0) sigma_inv[b * OUT_F + o] = rsqrtf(v + EPSV);
  }
}

// ---- zero the halo border cells of every (ic,b) plane ----
__global__ void k_zero_border(char* __restrict__ xmp) {
  const int plane = blockIdx.x;           // 128 planes
  char* base = xmp + (size_t)plane * (66 * 66 * 64);
  for (int idx = threadIdx.x; idx < 1040; idx += 256) {  // 260 cells * 4 parts
    const int c = idx >> 2, part = idx & 3;
    int hp, wp;
    if (c < 66)       { hp = 0;          wp = c; }
    else if (c < 132) { hp = 65;         wp = c - 66; }
    else if (c < 196) { hp = c - 132 + 1; wp = 0; }
    else              { hp = c - 196 + 1; wp = 65; }
    *(uint4*)(base + ((size_t)hp * 66 + wp) * 64 + part * 16) = make_uint4(0u, 0u, 0u, 0u);
  }
}

// ---- xmp[ic][b][h+1][w+1][32ch] = bf16(x[b][ic*32+ch][h][w] * s) ----
__global__ void k_modulate(const float* __restrict__ x,
                           const float* __restrict__ s,
                           char* __restrict__ xmp) {
  const int h  = blockIdx.x & 63;
  const int ic = (blockIdx.x >> 6) & 15;
  const int b  = blockIdx.x >> 10;
  __shared__ float tile[32][65];
  const int tid = threadIdx.x;
  {
    const int il = tid >> 3, w8 = (tid & 7) * 8;
    const int i = ic * 32 + il;
    const float sv = s[b * IN_F + i];
    const float* xp = x + (((size_t)(b * IN_F + i) * RES + h) * RES + w8);
    const float4 v0 = *(const float4*)xp;
    const float4 v1 = *(const float4*)(xp + 4);
    tile[il][w8 + 0] = v0.x * sv; tile[il][w8 + 1] = v0.y * sv;
    tile[il][w8 + 2] = v0.z * sv; tile[il][w8 + 3] = v0.w * sv;
    tile[il][w8 + 4] = v1.x * sv; tile[il][w8 + 5] = v1.y * sv;
    tile[il][w8 + 6] = v1.z * sv; tile[il][w8 + 7] = v1.w * sv;
  }
  __syncthreads();
  {
    const int w = tid >> 2, part = tid & 3;
    short8 pk;
#pragma unroll
    for (int j = 0; j < 8; ++j) {
      BF cv; cv.h = __float2bfloat16(tile[part * 8 + j][w]);
      pk[j] = cv.s;
    }
    char* dst = xmp + ((size_t)((ic * 8 + b) * 66 + (h + 1)) * 66 + (w + 1)) * 64 + part * 16;
    *(short8*)dst = pk;
  }
}

// ---------------- main implicit-GEMM conv ----------------
// Block: 64 o-chans x (8 rows x 64 cols) pixels, 4 waves (wave = 2 rows).
// LDS: xs = 10 halo rows x 66 cols x 32ch (XOR-swizzled 64B cells) staged once
// per ic-chunk via global_load_lds; wsm = 3 taps x 64 o x 32ch staged per dh.
__global__ __launch_bounds__(256, 2)
void k_conv(const char* __restrict__ xmp,
            const short* __restrict__ wb,
            const float* __restrict__ sigma_inv,
            const float* __restrict__ b_conv,
            float* __restrict__ out) {
  __shared__ __align__(16) char lds[57344];   // xs: 0..45056 (slack incl), wsm: 45056..57344
  char* const wsm = lds + 45056;
  const int o0 = blockIdx.x * 64;
  const int b  = blockIdx.y >> 3;
  const int h0 = (blockIdx.y & 7) * 8;
  const int tid = threadIdx.x;
  const int wave = tid >> 6, lane = tid & 63;
  const int lo = lane & 15, quad = lane >> 4;
  const int qb = quad * 16;

  f32x4 acc[8][4];
#pragma unroll
  for (int i = 0; i < 8; ++i)
#pragma unroll
    for (int j = 0; j < 4; ++j) acc[i][j] = (f32x4){0.f, 0.f, 0.f, 0.f};

  for (int ic = 0; ic < 16; ++ic) {
    const char* xr = xmp + (size_t)((ic * 8 + b) * 66 + h0) * (66 * 64);
    const char* wr = (const char*)(wb + (size_t)(ic * 9) * OUT_F * 32) + (size_t)o0 * 64;
#pragma unroll 1
    for (int dh = 0; dh < 3; ++dh) {
      __syncthreads();
      if (dh == 0) {
        // stage 2640 16B chunks (10 rows x 66 cols x 4 parts), swizzle-placed
#pragma unroll
        for (int k = 0; k < 11; ++k) {
          const int j = tid + k * 256;
          const int jj = j > 2639 ? 2639 : j;
          const int p = jj >> 2;
          const int q = (jj & 3) ^ ((p >> 1) & 3);
          async_load16(xr + p * 64 + q * 16, lds + j * 16);
        }
      }
      // stage 768 chunks of weights: taps dh*3..dh*3+2, 64 o, 32 ch
#pragma unroll
      for (int k = 0; k < 3; ++k) {
        const int j = k * 256 + tid;
        const int cell = j >> 2;                  // k*64 + ol
        const int q = (j & 3) ^ ((cell >> 1) & 3);
        const int ol = cell & 63;
        async_load16(wr + (size_t)((dh * 3 + k) * OUT_F + ol) * 64 + q * 16, wsm + j * 16);
      }
      __syncthreads();
#pragma unroll
      for (int dw = 0; dw < 3; ++dw) {
        const int cb = dw * 64 + lo;
        const int baddr = ((cb << 6) | qb) ^ ((cb << 3) & 0x30);
        short8 bf[4];
#pragma unroll
        for (int ns = 0; ns < 4; ++ns)
          bf[ns] = *(const short8*)(wsm + baddr + ns * 1024);
#pragma unroll
        for (int row = 0; row < 2; ++row) {
          const int p0 = (wave * 2 + row + dh) * 66 + dw + lo;
          const int aaddr = ((p0 << 6) | qb) ^ ((p0 << 3) & 0x30);
#pragma unroll
          for (int seg = 0; seg < 4; ++seg) {
            const short8 af = *(const short8*)(lds + aaddr + seg * 1024);
#pragma unroll
            for (int ns = 0; ns < 4; ++ns)
              acc[row * 4 + seg][ns] =
                  __builtin_amdgcn_mfma_f32_16x16x32_bf16(af, bf[ns], acc[row * 4 + seg][ns], 0, 0, 0);
          }
        }
      }
    }
  }
  // epilogue: y = acc * sigma_inv + bias   (D: col(o)=lane&15, row(px)=quad*4+reg)
#pragma unroll
  for (int ns = 0; ns < 4; ++ns) {
    const int o = o0 + ns * 16 + lo;
    const float sig  = sigma_inv[b * OUT_F + o];
    const float bias = b_conv[o];
#pragma unroll
    for (int row = 0; row < 2; ++row) {
      float* op = out + ((size_t)(b * OUT_F + o) * RES + (h0 + wave * 2 + row)) * RES;
#pragma unroll
      for (int seg = 0; seg < 4; ++seg) {
        f32x4 v;
#pragma unroll
        for (int r = 0; r < 4; ++r) v[r] = acc[row * 4 + seg][ns][r] * sig + bias;
        *(f32x4*)(op + seg * 16 + quad * 4) = v;
      }
    }
  }
}

extern "C" void kernel_launch(void* const* d_in, const int* in_sizes, int n_in,
                              void* d_out, int out_size, void* d_ws, size_t ws_size,
                              hipStream_t stream) {
  const float* x      = (const float*)d_in[0];
  const float* latent = (const float*)d_in[1];
  const float* w_lin  = (const float*)d_in[2];
  const float* b_lin  = (const float*)d_in[3];
  const float* w_conv = (const float*)d_in[4];
  const float* b_conv = (const float*)d_in[5];
  float* out = (float*)d_out;

  char* ws = (char*)d_ws;
  char*  xmp       = ws;                               // 35,684,352 B (16*8*66*66*64)
  short* wb        = (short*)(ws + 35684352);          //  4,718,592 B
  float* s         = (float*)(ws + 40402944);          //     16,384 B
  float* sigma_inv = (float*)(ws + 40419328);          //     16,384 B

  k_compute_s<<<IN_F, 64, 0, stream>>>(latent, w_lin, b_lin, s);
  k_prep_w<<<1152, 256, 0, stream>>>(w_conv, wb);
  k_sigma<<<OUT_F, 64, 0, stream>>>(w_conv, s, sigma_inv);
  k_zero_border<<<128, 256, 0, stream>>>(xmp);
  k_modulate<<<BATCH * 16 * RES, 256, 0, stream>>>(x, s, xmp);
  dim3 grid(OUT_F / 64, BATCH * 8);
  k_conv<<<grid, 256, 0, stream>>>(xmp, wb, sigma_inv, b_conv, out);
}

// Round 3
// 252.981 us; speedup vs baseline: 1.3380x; 1.0813x over previous
//
#include <hip/hip_runtime.h>
#include <hip/hip_bf16.h>

#define IN_F 512
#define OUT_F 512
#define LATD 512
#define RES 64
#define BATCH 8
#define EPSV 1e-8f

static constexpr float C_LIN  = 0.04419417382415922f;   // 1/sqrt(512)
static constexpr float C_CONV = 0.014731391274719739f;  // 1/sqrt(512*9)

typedef __attribute__((ext_vector_type(8)))  short short8;
typedef __attribute__((ext_vector_type(16))) float f32x16;

union BF { __hip_bfloat16 h; short s; };

__device__ __forceinline__ void async_load16(const char* g, char* l) {
  __builtin_amdgcn_global_load_lds(
      (const __attribute__((address_space(1))) unsigned int*)g,
      (__attribute__((address_space(3))) unsigned int*)l, 16, 0, 0);
}

// ---------------- s = latent @ (w_lin*C).T + b_lin ----------------
__global__ void k_compute_s(const float* __restrict__ latent,
                            const float* __restrict__ w_lin,
                            const float* __restrict__ b_lin,
                            float* __restrict__ s) {
  const int i = blockIdx.x;
  const int lane = threadIdx.x;
  const float4* wl = (const float4*)(w_lin + (size_t)i * LATD);
  const float4 w0 = wl[lane * 2], w1 = wl[lane * 2 + 1];
  float acc[BATCH];
#pragma unroll
  for (int b = 0; b < BATCH; ++b) {
    const float4* lt = (const float4*)(latent + (size_t)b * LATD);
    const float4 l0 = lt[lane * 2], l1 = lt[lane * 2 + 1];
    acc[b] = w0.x * l0.x + w0.y * l0.y + w0.z * l0.z + w0.w * l0.w +
             w1.x * l1.x + w1.y * l1.y + w1.z * l1.z + w1.w * l1.w;
  }
#pragma unroll
  for (int b = 0; b < BATCH; ++b) {
    float v = acc[b];
#pragma unroll
    for (int off = 32; off > 0; off >>= 1) v += __shfl_down(v, off);
    if (lane == 0) s[b * IN_F + i] = v * C_LIN + b_lin[i];
  }
}

// ---- wb[c16][ob][tap][ol][16ch] = bf16(w_conv*C) ; w2[o][i] = sum_t w^2 ----
__global__ void k_prep_w(const float* __restrict__ w_conv,
                         short* __restrict__ wb,
                         float* __restrict__ w2) {
  const int t = blockIdx.x * 256 + threadIdx.x;   // 262144: o*512 + i
  const int o = t >> 9;
  const int i = t & 511;
  const float* src = w_conv + (size_t)t * 9;
  const int c = i >> 4, ob = o >> 6, ol = o & 63, i16 = i & 15;
  float sum = 0.f;
#pragma unroll
  for (int tap = 0; tap < 9; ++tap) {
    const float v = src[tap] * C_CONV;
    sum += v * v;
    BF cv; cv.h = __float2bfloat16(v);
    wb[(size_t)((c * 8 + ob) * 9 + tap) * 1024 + ol * 16 + i16] = cv.s;
  }
  w2[t] = sum;
}

// ---- sigma_inv[b][o] = rsqrt(sum_i w2[o][i]*s[b][i]^2 + eps) ----
__global__ void k_sigma(const float* __restrict__ w2,
                        const float* __restrict__ s,
                        float* __restrict__ sigma_inv) {
  const int o = blockIdx.x * 4 + (threadIdx.x >> 6);
  const int lane = threadIdx.x & 63;
  float acc[BATCH];
#pragma unroll
  for (int b = 0; b < BATCH; ++b) acc[b] = 0.f;
#pragma unroll
  for (int k = 0; k < 8; ++k) {
    const int i = k * 64 + lane;
    const float w = w2[o * IN_F + i];
#pragma unroll
    for (int b = 0; b < BATCH; ++b) {
      const float sv = s[b * IN_F + i];
      acc[b] += w * sv * sv;
    }
  }
#pragma unroll
  for (int b = 0; b < BATCH; ++b) {
    float v = acc[b];
#pragma unroll
    for (int off = 32; off > 0; off >>= 1) v += __shfl_down(v, off);
    if (lane == 0) sigma_inv[b * OUT_F + o] = rsqrtf(v + EPSV);
  }
}

// ---- zero halo borders of all 256 (c16,b) planes (66x66 cells of 32B) ----
__global__ void k_zero_border(char* __restrict__ xmp) {
  char* base = xmp + (size_t)blockIdx.x * 139392;
  for (int q = threadIdx.x; q < 520; q += 256) {     // 260 cells * 2 halves
    const int cell = q >> 1, half = q & 1;
    int hp, wp;
    if (cell < 66)       { hp = 0;              wp = cell; }
    else if (cell < 132) { hp = 65;             wp = cell - 66; }
    else if (cell < 196) { hp = cell - 132 + 1; wp = 0; }
    else                 { hp = cell - 196 + 1; wp = 65; }
    *(uint4*)(base + ((size_t)hp * 66 + wp) * 32 + half * 16) = make_uint4(0u, 0u, 0u, 0u);
  }
}

// ---- xmp[c16][b][h+1][w+1][16ch] = bf16(x[b][i][h][w] * s[b][i]) ----
__global__ void k_modulate(const float* __restrict__ x,
                           const float* __restrict__ s,
                           char* __restrict__ xmp) {
  const int h    = blockIdx.x & 63;
  const int ic32 = (blockIdx.x >> 6) & 15;
  const int b    = blockIdx.x >> 10;
  __shared__ float tile[32][65];
  const int tid = threadIdx.x;
  {
    const int il = tid >> 3, w8 = (tid & 7) * 8;
    const int i = ic32 * 32 + il;
    const float sv = s[b * IN_F + i];
    const float* xp = x + (((size_t)(b * IN_F + i) * RES + h) * RES + w8);
    const float4 v0 = *(const float4*)xp;
    const float4 v1 = *(const float4*)(xp + 4);
    tile[il][w8 + 0] = v0.x * sv; tile[il][w8 + 1] = v0.y * sv;
    tile[il][w8 + 2] = v0.z * sv; tile[il][w8 + 3] = v0.w * sv;
    tile[il][w8 + 4] = v1.x * sv; tile[il][w8 + 5] = v1.y * sv;
    tile[il][w8 + 6] = v1.z * sv; tile[il][w8 + 7] = v1.w * sv;
  }
  __syncthreads();
  {
    const int w = tid >> 2, part = tid & 3;
    const int chalf = part >> 1, half = part & 1;
    short8 pk;
#pragma unroll
    for (int j = 0; j < 8; ++j) {
      BF cv; cv.h = __float2bfloat16(tile[chalf * 16 + half * 8 + j][w]);
      pk[j] = cv.s;
    }
    const int c = ic32 * 2 + chalf;
    char* dst = xmp + (size_t)(c * 8 + b) * 139392 +
                ((size_t)(h + 1) * 66 + (w + 1)) * 32 + half * 16;
    *(short8*)dst = pk;
  }
}

// ---------------- main implicit-GEMM conv ----------------
// Block: 64 o x (8 rows x 64 cols), 4 waves (wave = 2 rows = 128 px).
// MFMA 32x32x16: A = weights (m=o), B = pixels (n=px) -> C/D col = px
// (coalesced NCHW stores). K=16 chunks, double-buffered LDS, 1 barrier/chunk.
__global__ __launch_bounds__(256, 2)
void k_conv(const char* __restrict__ xmp,
            const short* __restrict__ wbg,
            const float* __restrict__ sigma_inv,
            const float* __restrict__ b_conv,
            float* __restrict__ out) {
  __shared__ __align__(16) char lds[79104];  // x: 2*21120, w: 2*18432
  const int ob = blockIdx.x;
  const int o0 = ob * 64;
  const int b  = blockIdx.y >> 3;
  const int h0 = (blockIdx.y & 7) * 8;
  const int tid = threadIdx.x;
  const int wave = tid >> 6, lane = tid & 63;
  const int l31 = lane & 31, half = lane >> 5;

  f32x16 acc[2][4];
#pragma unroll
  for (int i = 0; i < 2; ++i)
#pragma unroll
    for (int j = 0; j < 4; ++j)
#pragma unroll
      for (int r = 0; r < 16; ++r) acc[i][j][r] = 0.f;

  const char* xsrc0 = xmp + (size_t)b * 139392 + (size_t)h0 * 2112;  // + ic*8*139392
  const char* wsrc0 = (const char*)wbg + (size_t)ob * 18432;          // + ic*8*18432

  // stage chunk 0 into parity 0
#pragma unroll
  for (int k = 0; k < 5; ++k) {
    const int j = tid + k * 256;
    async_load16(xsrc0 + j * 16, lds + j * 16);
  }
  if (tid < 40) { const int j = 1280 + tid; async_load16(xsrc0 + j * 16, lds + j * 16); }
#pragma unroll
  for (int k = 0; k < 4; ++k) {
    const int j = tid + k * 256;
    async_load16(wsrc0 + j * 16, lds + 42240 + j * 16);
  }
  if (tid < 128) { const int j = 1024 + tid; async_load16(wsrc0 + j * 16, lds + 42240 + j * 16); }
  __syncthreads();

  for (int ic = 0; ic < 32; ++ic) {
    const int p = ic & 1;
    if (ic + 1 < 32) {     // prefetch next chunk into parity p^1
      const char* xs = xsrc0 + (size_t)(ic + 1) * (8 * 139392);
      const char* wsr = wsrc0 + (size_t)(ic + 1) * (8 * 18432);
      char* xd = lds + (p ^ 1) * 21120;
      char* wd = lds + 42240 + (p ^ 1) * 18432;
#pragma unroll
      for (int k = 0; k < 5; ++k) {
        const int j = tid + k * 256;
        async_load16(xs + j * 16, xd + j * 16);
      }
      if (tid < 40) { const int j = 1280 + tid; async_load16(xs + j * 16, xd + j * 16); }
#pragma unroll
      for (int k = 0; k < 4; ++k) {
        const int j = tid + k * 256;
        async_load16(wsr + j * 16, wd + j * 16);
      }
      if (tid < 128) { const int j = 1024 + tid; async_load16(wsr + j * 16, wd + j * 16); }
    }
    const char* xp = lds + p * 21120;
    const char* wp = lds + 42240 + p * 18432;
#pragma unroll
    for (int tap = 0; tap < 9; ++tap) {
      const int dh = tap / 3, dw = tap - dh * 3;
      const short8 a0 = *(const short8*)(wp + (tap * 64 + l31) * 32 + half * 16);
      const short8 a1 = *(const short8*)(wp + (tap * 64 + 32 + l31) * 32 + half * 16);
#pragma unroll
      for (int tp = 0; tp < 4; ++tp) {
        const int hr = wave * 2 + (tp >> 1) + dh;
        const int wc = (tp & 1) * 32 + dw + l31;
        const short8 bf = *(const short8*)(xp + (hr * 66 + wc) * 32 + half * 16);
        acc[0][tp] = __builtin_amdgcn_mfma_f32_32x32x16_bf16(a0, bf, acc[0][tp], 0, 0, 0);
        acc[1][tp] = __builtin_amdgcn_mfma_f32_32x32x16_bf16(a1, bf, acc[1][tp], 0, 0, 0);
      }
    }
    __syncthreads();
  }

  // epilogue: C/D col(lane&31) = px-within-32, row = o_local
  // o_local = (reg&3) + 8*(reg>>2) + 4*half + 32*t_o ; px: h = h0+wave*2+(tp>>1), w = (tp&1)*32 + l31
#pragma unroll
  for (int t_o = 0; t_o < 2; ++t_o) {
#pragma unroll
    for (int g = 0; g < 4; ++g) {
#pragma unroll
      for (int r = 0; r < 4; ++r) {
        const int o = o0 + t_o * 32 + r + 8 * g + 4 * half;
        const float sig  = sigma_inv[b * OUT_F + o];
        const float bias = b_conv[o];
        const int reg = g * 4 + r;
#pragma unroll
        for (int tp = 0; tp < 4; ++tp) {
          const int h = h0 + wave * 2 + (tp >> 1);
          const int w = (tp & 1) * 32 + l31;
          out[(((size_t)(b * OUT_F + o) * RES + h) * RES) + w] =
              acc[t_o][tp][reg] * sig + bias;
        }
      }
    }
  }
}

extern "C" void kernel_launch(void* const* d_in, const int* in_sizes, int n_in,
                              void* d_out, int out_size, void* d_ws, size_t ws_size,
                              hipStream_t stream) {
  const float* x      = (const float*)d_in[0];
  const float* latent = (const float*)d_in[1];
  const float* w_lin  = (const float*)d_in[2];
  const float* b_lin  = (const float*)d_in[3];
  const float* w_conv = (const float*)d_in[4];
  const float* b_conv = (const float*)d_in[5];
  float* out = (float*)d_out;

  char* ws = (char*)d_ws;
  char*  xmp       = ws;                            // 35,684,352 B (256 planes x 66*66*32)
  short* wb        = (short*)(ws + 35684352);       //  4,718,592 B
  float* w2        = (float*)(ws + 40402944);       //  1,048,576 B
  float* s         = (float*)(ws + 41451520);       //     16,384 B
  float* sigma_inv = (float*)(ws + 41467904);       //     16,384 B

  k_compute_s<<<IN_F, 64, 0, stream>>>(latent, w_lin, b_lin, s);
  k_prep_w<<<1024, 256, 0, stream>>>(w_conv, wb, w2);
  k_sigma<<<128, 256, 0, stream>>>(w2, s, sigma_inv);
  k_zero_border<<<256, 256, 0, stream>>>(xmp);
  k_modulate<<<BATCH * 16 * RES, 256, 0, stream>>>(x, s, xmp);
  dim3 grid(OUT_F / 64, BATCH * 8);
  k_conv<<<grid, 256, 0, stream>>>(xmp, wb, sigma_inv, b_conv, out);
}